// Round 1
// 785.212 us; speedup vs baseline: 1.4486x; 1.4486x over previous
//
#include <hip/hip_runtime.h>

typedef unsigned short u16;
typedef unsigned int   u32;

#define DEVINL __device__ __forceinline__

// ---- problem constants (f32 problem: all float inputs/outputs are f32) --
#define NLOC 1024
#define NNEI 64
#define NDIM 128
#define EDIM 64
#define ADIM 64
#define ASEL 20

// ---- static device workspace -------------------------------------------
enum : size_t {
  WS_NSELF = 0,                        // [1024,128] silu(node@W_self+b)
  WS_NW0   = WS_NSELF + 1024*128,      // [1024,128] node@W0 + b_ne
  WS_NV0   = WS_NW0   + 1024*128,      // [1024,64]  node@V0 + b_es
  WS_NA1   = WS_NV0   + 1024*64,       // [1024,64]  node@A1 + b_ea1
  WS_NB1   = WS_NA1   + 1024*64,       // [1024,64]  node@B1 + b_as
  WS_F32_END = WS_NB1 + 1024*64
};
__device__ float g_ws[WS_F32_END];
__device__ float g_red[1024*ASEL*64];   // reduced (K2 -> K3)

DEVINL float siluf(float x) {
  return x * __builtin_amdgcn_rcpf(1.0f + __expf(-x));
}

// =========================================================================
// K0: per-node projections. grid=1024 x 128.
// =========================================================================
__global__ __launch_bounds__(128) void k0_node_pre(
    const float* __restrict__ node,
    const float* __restrict__ W_self, const float* __restrict__ b_self,
    const float* __restrict__ W_ne,   const float* __restrict__ b_ne,
    const float* __restrict__ W_es,   const float* __restrict__ b_es,
    const float* __restrict__ W_ea1,  const float* __restrict__ b_ea1,
    const float* __restrict__ W_as,   const float* __restrict__ b_as)
{
  const int l = blockIdx.x, t = threadIdx.x;
  __shared__ float nl[128];
  nl[t] = node[l*128 + t];
  __syncthreads();
  float aS = b_self[t];
  float aW = b_ne[t];
  #pragma unroll 8
  for (int k = 0; k < 128; ++k) {
    float nv = nl[k];
    aS = fmaf(nv, W_self[k*128 + t], aS);
    aW = fmaf(nv, W_ne[k*128 + t], aW);
  }
  g_ws[WS_NSELF + l*128 + t] = siluf(aS);
  g_ws[WS_NW0   + l*128 + t] = aW;
  if (t < 64) {
    float aV = b_es[t], aA = b_ea1[t], aB = b_as[t];
    #pragma unroll 8
    for (int k = 0; k < 128; ++k) {
      float nv = nl[k];
      aV = fmaf(nv, W_es[k*64 + t], aV);
      aA = fmaf(nv, W_ea1[(64 + k)*64 + t], aA);
      aB = fmaf(nv, W_as[(64 + k)*64 + t], aB);
    }
    g_ws[WS_NV0 + l*64 + t] = aV;
    g_ws[WS_NA1 + l*64 + t] = aA;
    g_ws[WS_NB1 + l*64 + t] = aB;
  }
}

// =========================================================================
// K2: angle kernel, rewritten as an LDS-staged register-blocked f32 GEMM.
//   Per block (one l): pre = ang(400x64) @ {A0,B0}(64x64) + broadcast terms.
//   Chunks of 64 rows staged in LDS (stride 68 -> conflict-free b128).
//   Thread tile: 4 rows x 4 cols, both GEMMs -> 32 accumulators in VGPRs.
//   A-branch: silu -> asw[j]-weighted LDS-atomic j-reduction -> g_red.
//   B-branch: silu -> residual add (orig row read back from LDS) -> out.
// =========================================================================
DEVINL void rank1(float a0, float a1, float a2, float a3, float4 w, float* acc) {
  acc[0]  = fmaf(a0, w.x, acc[0]);  acc[1]  = fmaf(a0, w.y, acc[1]);
  acc[2]  = fmaf(a0, w.z, acc[2]);  acc[3]  = fmaf(a0, w.w, acc[3]);
  acc[4]  = fmaf(a1, w.x, acc[4]);  acc[5]  = fmaf(a1, w.y, acc[5]);
  acc[6]  = fmaf(a1, w.z, acc[6]);  acc[7]  = fmaf(a1, w.w, acc[7]);
  acc[8]  = fmaf(a2, w.x, acc[8]);  acc[9]  = fmaf(a2, w.y, acc[9]);
  acc[10] = fmaf(a2, w.z, acc[10]); acc[11] = fmaf(a2, w.w, acc[11]);
  acc[12] = fmaf(a3, w.x, acc[12]); acc[13] = fmaf(a3, w.y, acc[13]);
  acc[14] = fmaf(a3, w.z, acc[14]); acc[15] = fmaf(a3, w.w, acc[15]);
}

__global__ __launch_bounds__(256, 2) void k2_angle(
    const float* __restrict__ ang,
    const float* __restrict__ edge,
    const float* __restrict__ a_sw,
    const float* __restrict__ res_a,
    const float* __restrict__ W_ea1, const float* __restrict__ W_as,
    float* __restrict__ angle_out)
{
  const int l = blockIdx.x, t = threadIdx.x;
  // 16B-aligned for float4 LDS access. Total ~76 KB -> 2 blocks/CU.
  __shared__ __align__(16) float angl[64*68];   // row chunk (also eang scratch)
  __shared__ __align__(16) float A0l[64*64];    // [k][c] natural layout
  __shared__ __align__(16) float B0l[64*64];
  __shared__ __align__(16) float eA2l[ASEL*68], eA3l[ASEL*68];
  __shared__ __align__(16) float eB2l[ASEL*68], eB3l[ASEL*68];
  __shared__ float red[ASEL*65];
  __shared__ __align__(16) float nA1l[64], nB1l[64], resal[64];
  __shared__ float aswl[ASEL];

  for (int e = t; e < ASEL*65; e += 256) red[e] = 0.f;
  // eang (edge rows 0..19) into angl scratch, stride 65
  for (int e = t; e < ASEL*64; e += 256)
    angl[(e >> 6)*65 + (e & 63)] = edge[(size_t)l*4096 + e];
  if (t < ASEL) aswl[t] = a_sw[l*ASEL + t];
  if (t < 64) {
    nA1l[t]  = g_ws[WS_NA1 + l*64 + t];
    nB1l[t]  = g_ws[WS_NB1 + l*64 + t];
    resal[t] = res_a[t];
  }
  // A0 = W_ea1 rows 0..63, B0 = W_as rows 0..63, kept in [k][c] layout:
  // per-k column reads are 16 lanes at float4 stride -> 2-way alias (free).
  for (int e = t; e < 4096; e += 256) { A0l[e] = W_ea1[e]; B0l[e] = W_as[e]; }
  __syncthreads();

  // stage-1: e_ang @ {A2,A3,B2,B3}; weights straight from L2 (64 KB total,
  // shared by all 1024 blocks), 5 j-accumulators amortize each weight load.
  {
    const int o = t & 63, wv = t >> 6;
    #pragma unroll 1
    for (int m = 0; m < 4; ++m) {
      const float* __restrict__ Wp =
            (m == 0) ? (W_ea1 + 192*64)
          : (m == 1) ? (W_ea1 + 256*64)
          : (m == 2) ? (W_as  + 192*64)
          :            (W_as  + 256*64);
      float* outm = (m == 0) ? eA2l : (m == 1) ? eA3l : (m == 2) ? eB2l : eB3l;
      float a0 = 0.f, a1 = 0.f, a2 = 0.f, a3 = 0.f, a4 = 0.f;
      #pragma unroll 4
      for (int k = 0; k < 64; ++k) {
        float w = Wp[k*64 + o];
        a0 = fmaf(angl[(wv     )*65 + k], w, a0);
        a1 = fmaf(angl[(wv +  4)*65 + k], w, a1);
        a2 = fmaf(angl[(wv +  8)*65 + k], w, a2);
        a3 = fmaf(angl[(wv + 12)*65 + k], w, a3);
        a4 = fmaf(angl[(wv + 16)*65 + k], w, a4);
      }
      outm[(wv     )*68 + o] = a0;
      outm[(wv +  4)*68 + o] = a1;
      outm[(wv +  8)*68 + o] = a2;
      outm[(wv + 12)*68 + o] = a3;
      outm[(wv + 16)*68 + o] = a4;
    }
  }

  const int tx = t & 15, ty = t >> 4;
  const int c0 = tx*4, r0 = ty*4;

  #pragma unroll 1
  for (int ch = 0; ch < 7; ++ch) {
    const int rb = ch*64;
    __syncthreads();          // previous users of angl are done
    // stage 64 ang rows (zero-pad past 400), coalesced float4
    for (int e = t*4; e < 4096; e += 1024) {
      int rr = e >> 6, c = e & 63;
      int r = rb + rr;
      float4 v;
      if (r < 400) v = *reinterpret_cast<const float4*>(ang + ((size_t)l*400 + r)*64 + c);
      else         v = make_float4(0.f, 0.f, 0.f, 0.f);
      *reinterpret_cast<float4*>(&angl[rr*68 + c]) = v;
    }
    __syncthreads();

    float accA[16], accB[16];
    #pragma unroll
    for (int q = 0; q < 16; ++q) { accA[q] = 0.f; accB[q] = 0.f; }

    #pragma unroll 2
    for (int k = 0; k < 64; k += 4) {
      float4 v0 = *reinterpret_cast<const float4*>(&angl[(r0+0)*68 + k]);
      float4 v1 = *reinterpret_cast<const float4*>(&angl[(r0+1)*68 + k]);
      float4 v2 = *reinterpret_cast<const float4*>(&angl[(r0+2)*68 + k]);
      float4 v3 = *reinterpret_cast<const float4*>(&angl[(r0+3)*68 + k]);
      float4 w;
      w = *reinterpret_cast<const float4*>(&A0l[(k+0)*64 + c0]); rank1(v0.x, v1.x, v2.x, v3.x, w, accA);
      w = *reinterpret_cast<const float4*>(&A0l[(k+1)*64 + c0]); rank1(v0.y, v1.y, v2.y, v3.y, w, accA);
      w = *reinterpret_cast<const float4*>(&A0l[(k+2)*64 + c0]); rank1(v0.z, v1.z, v2.z, v3.z, w, accA);
      w = *reinterpret_cast<const float4*>(&A0l[(k+3)*64 + c0]); rank1(v0.w, v1.w, v2.w, v3.w, w, accA);
      w = *reinterpret_cast<const float4*>(&B0l[(k+0)*64 + c0]); rank1(v0.x, v1.x, v2.x, v3.x, w, accB);
      w = *reinterpret_cast<const float4*>(&B0l[(k+1)*64 + c0]); rank1(v0.y, v1.y, v2.y, v3.y, w, accB);
      w = *reinterpret_cast<const float4*>(&B0l[(k+2)*64 + c0]); rank1(v0.z, v1.z, v2.z, v3.z, w, accB);
      w = *reinterpret_cast<const float4*>(&B0l[(k+3)*64 + c0]); rank1(v0.w, v1.w, v2.w, v3.w, w, accB);
    }

    #pragma unroll
    for (int ri = 0; ri < 4; ++ri) {
      int r = rb + r0 + ri;
      if (r < 400) {
        int i = r / 20, j = r % 20;
        float aswj = aswl[j];
        float4 nA  = *reinterpret_cast<const float4*>(&nA1l[c0]);
        float4 nB  = *reinterpret_cast<const float4*>(&nB1l[c0]);
        float4 e2A = *reinterpret_cast<const float4*>(&eA2l[j*68 + c0]);
        float4 e3A = *reinterpret_cast<const float4*>(&eA3l[i*68 + c0]);
        float4 e2B = *reinterpret_cast<const float4*>(&eB2l[j*68 + c0]);
        float4 e3B = *reinterpret_cast<const float4*>(&eB3l[i*68 + c0]);
        float4 orig = *reinterpret_cast<const float4*>(&angl[(r0+ri)*68 + c0]);
        float4 rv   = *reinterpret_cast<const float4*>(&resal[c0]);
        float pA0 = accA[ri*4+0] + nA.x + e2A.x + e3A.x;
        float pA1 = accA[ri*4+1] + nA.y + e2A.y + e3A.y;
        float pA2 = accA[ri*4+2] + nA.z + e2A.z + e3A.z;
        float pA3 = accA[ri*4+3] + nA.w + e2A.w + e3A.w;
        atomicAdd(&red[i*65 + c0+0], aswj * siluf(pA0));
        atomicAdd(&red[i*65 + c0+1], aswj * siluf(pA1));
        atomicAdd(&red[i*65 + c0+2], aswj * siluf(pA2));
        atomicAdd(&red[i*65 + c0+3], aswj * siluf(pA3));
        float pB0 = accB[ri*4+0] + nB.x + e2B.x + e3B.x;
        float pB1 = accB[ri*4+1] + nB.y + e2B.y + e3B.y;
        float pB2 = accB[ri*4+2] + nB.z + e2B.z + e3B.z;
        float pB3 = accB[ri*4+3] + nB.w + e2B.w + e3B.w;
        float4 outv;
        outv.x = orig.x + rv.x * siluf(pB0);
        outv.y = orig.y + rv.y * siluf(pB1);
        outv.z = orig.z + rv.z * siluf(pB2);
        outv.w = orig.w + rv.w * siluf(pB3);
        *reinterpret_cast<float4*>(angle_out + ((size_t)l*400 + r)*64 + c0) = outv;
      }
    }
  }
  __syncthreads();
  const float rs = 0.22360679775f;   // 1/sqrt(20)
  for (int e = t; e < ASEL*64; e += 256) {
    int i = e >> 6, d = e & 63;
    g_red[((size_t)l*ASEL + i)*64 + d] = aswl[i] * red[i*65 + d] * rs;
  }
}

// =========================================================================
// K3: node + edge kernel. grid=1024 x 256.
// =========================================================================
__global__ __launch_bounds__(256) void k3_node_edge(
    const float* __restrict__ node_ext,
    const float* __restrict__ edge,
    const float* __restrict__ h2,
    const float* __restrict__ sw,
    const int* __restrict__ nlist,
    const float* __restrict__ W_sym, const float* __restrict__ b_sym,
    const float* __restrict__ W_ne,  const float* __restrict__ W_es,
    const float* __restrict__ W_ea2, const float* __restrict__ b_ea2,
    const float* __restrict__ res_n, const float* __restrict__ res_e,
    float* __restrict__ node_out,
    float* __restrict__ edge_out)
{
  const int l = blockIdx.x, t = threadIdx.x;
  __shared__ float Ef[64*64];
  __shared__ float Nf[64*128];
  __shared__ float hwv[64*4];
  __shared__ float swl[64];
  __shared__ float hgE[3*64], hgN[3*128];
  __shared__ float cat[768];
  __shared__ float nsym[128];
  __shared__ float msgl[ASEL*64];
  __shared__ float msgc[64];

  for (int e = t; e < 4096; e += 256) Ef[e] = edge[l*4096 + e];
  for (int e = t; e < 8192; e += 256) {
    int n = e >> 7, k = e & 127;
    int idx = nlist[l*64 + n];
    Nf[e] = node_ext[(size_t)idx*128 + k];
  }
  if (t < 64) {
    float s = sw[l*64 + t];
    swl[t] = s;
    hwv[t*4+0] = h2[(l*64 + t)*3 + 0] * s;
    hwv[t*4+1] = h2[(l*64 + t)*3 + 1] * s;
    hwv[t*4+2] = h2[(l*64 + t)*3 + 2] * s;
  }
  __syncthreads();

  // hg = (h2*sw)^T @ G / 64
  for (int e = t; e < 192; e += 256) {
    int tt = e >> 6, d = e & 63;
    float acc = 0.f;
    #pragma unroll 4
    for (int n = 0; n < 64; ++n) acc = fmaf(hwv[n*4 + tt], Ef[n*64 + d], acc);
    hgE[tt*64 + d] = acc * (1.f/64.f);
  }
  for (int e = t; e < 384; e += 256) {
    int tt = e >> 7, k = e & 127;
    float acc = 0.f;
    #pragma unroll 4
    for (int n = 0; n < 64; ++n) acc = fmaf(hwv[n*4 + tt], Nf[n*128 + k], acc);
    hgN[tt*128 + k] = acc * (1.f/64.f);
  }
  __syncthreads();

  // cat = [grrg(edge)(4x64), grrg(nei)(4x128)]
  for (int e = t; e < 256; e += 256) {
    int a = e >> 6, d = e & 63;
    cat[e] = (hgE[a]*hgE[d] + hgE[64 + a]*hgE[64 + d] + hgE[128 + a]*hgE[128 + d]) * (1.f/3.f);
  }
  for (int e = t; e < 512; e += 256) {
    int a = e >> 7, k = e & 127;
    cat[256 + e] = (hgN[a]*hgN[k] + hgN[128 + a]*hgN[128 + k] + hgN[256 + a]*hgN[256 + k]) * (1.f/3.f);
  }
  __syncthreads();

  // node_sym (threads 0-127) and e_angle_msg (threads 128-255)
  if (t < 128) {
    float acc = b_sym[t];
    #pragma unroll 4
    for (int c = 0; c < 768; ++c)
      acc = fmaf(cat[c], W_sym[c*128 + t], acc);
    nsym[t] = siluf(acc);
  } else {
    int idx = t - 128;
    if (idx < 64) msgc[idx] = siluf(b_ea2[idx]);
    for (int q = 0; q < 10; ++q) {
      int e = q*128 + idx;
      int n = e >> 6, oo = e & 63;
      float acc = b_ea2[oo];
      #pragma unroll 4
      for (int k = 0; k < 64; ++k)
        acc = fmaf(g_red[(l*ASEL + n)*64 + k], W_ea2[k*64 + oo], acc);
      msgl[e] = siluf(acc);
    }
  }
  __syncthreads();

  // main GEMM: 64 nei-rows x (128 ne-cols + 64 es-cols)
  if (t < 128) {
    const int c = t;
    float colbase = g_ws[WS_NW0 + l*128 + c];
    float nedge = 0.f;
    for (int nt4 = 0; nt4 < 4; ++nt4) {
      float acc[16];
      #pragma unroll
      for (int nn = 0; nn < 16; ++nn) acc[nn] = colbase;
      #pragma unroll 4
      for (int k = 0; k < 128; ++k) {
        float w = W_ne[(128 + k)*128 + c];
        #pragma unroll
        for (int nn = 0; nn < 16; ++nn)
          acc[nn] = fmaf(Nf[(nt4*16 + nn)*128 + k], w, acc[nn]);
      }
      #pragma unroll 4
      for (int k = 0; k < 64; ++k) {
        float w = W_ne[(256 + k)*128 + c];
        #pragma unroll
        for (int nn = 0; nn < 16; ++nn)
          acc[nn] = fmaf(Ef[(nt4*16 + nn)*64 + k], w, acc[nn]);
      }
      #pragma unroll
      for (int nn = 0; nn < 16; ++nn)
        nedge = fmaf(siluf(acc[nn]), swl[nt4*16 + nn], nedge);
    }
    nedge *= (1.f/64.f);
    float nodev = node_ext[l*128 + c];
    float outv = nodev + res_n[c]*g_ws[WS_NSELF + l*128 + c]
               + res_n[128 + c]*nsym[c] + res_n[256 + c]*nedge;
    node_out[l*128 + c] = outv;
  } else if (t < 192) {
    const int o = t - 128;
    float colbase = g_ws[WS_NV0 + l*64 + o];
    float re0 = res_e[o], re1 = res_e[64 + o];
    float msgcv = msgc[o];
    for (int nt4 = 0; nt4 < 4; ++nt4) {
      float acc[16];
      #pragma unroll
      for (int nn = 0; nn < 16; ++nn) acc[nn] = colbase;
      #pragma unroll 4
      for (int k = 0; k < 128; ++k) {
        float w = W_es[(128 + k)*64 + o];
        #pragma unroll
        for (int nn = 0; nn < 16; ++nn)
          acc[nn] = fmaf(Nf[(nt4*16 + nn)*128 + k], w, acc[nn]);
      }
      #pragma unroll 4
      for (int k = 0; k < 64; ++k) {
        float w = W_es[(256 + k)*64 + o];
        #pragma unroll
        for (int nn = 0; nn < 16; ++nn)
          acc[nn] = fmaf(Ef[(nt4*16 + nn)*64 + k], w, acc[nn]);
      }
      #pragma unroll
      for (int nn = 0; nn < 16; ++nn) {
        int n = nt4*16 + nn;
        float s = siluf(acc[nn]);
        float msgv = (n < ASEL) ? msgl[n*64 + o] : msgcv;
        edge_out[(size_t)l*4096 + n*64 + o] = Ef[n*64 + o] + re0*s + re1*msgv;
      }
    }
  }
}

// =========================================================================
extern "C" void kernel_launch(void* const* d_in, const int* in_sizes, int n_in,
                              void* d_out, int out_size, void* d_ws, size_t ws_size,
                              hipStream_t stream) {
  const float* node_ext = (const float*)d_in[0];
  const float* edge_ebd = (const float*)d_in[1];
  const float* h2       = (const float*)d_in[2];
  const float* angle    = (const float*)d_in[3];
  const float* sw       = (const float*)d_in[4];
  const float* a_sw     = (const float*)d_in[5];
  const float* W_self   = (const float*)d_in[6];
  const float* b_self   = (const float*)d_in[7];
  const float* W_sym    = (const float*)d_in[8];
  const float* b_sym    = (const float*)d_in[9];
  const float* W_ne     = (const float*)d_in[10];
  const float* b_ne     = (const float*)d_in[11];
  const float* W_es     = (const float*)d_in[12];
  const float* b_es     = (const float*)d_in[13];
  const float* W_ea1    = (const float*)d_in[14];
  const float* b_ea1    = (const float*)d_in[15];
  const float* W_ea2    = (const float*)d_in[16];
  const float* b_ea2    = (const float*)d_in[17];
  const float* W_as     = (const float*)d_in[18];
  const float* b_as     = (const float*)d_in[19];
  const float* res_n    = (const float*)d_in[20];
  const float* res_e    = (const float*)d_in[21];
  const float* res_a    = (const float*)d_in[22];
  const int*   nlist    = (const int*)d_in[23];

  float* out = (float*)d_out;
  float* node_out  = out;
  float* edge_out  = out + 1024*128;
  float* angle_out = out + 1024*128 + (size_t)1024*64*64;

  k0_node_pre<<<1024, 128, 0, stream>>>(node_ext, W_self, b_self, W_ne, b_ne,
                                        W_es, b_es, W_ea1, b_ea1, W_as, b_as);
  k2_angle<<<1024, 256, 0, stream>>>(angle, edge_ebd, a_sw, res_a,
                                     W_ea1, W_as, angle_out);
  k3_node_edge<<<1024, 256, 0, stream>>>(node_ext, edge_ebd, h2, sw, nlist,
                                         W_sym, b_sym, W_ne, W_es, W_ea2, b_ea2,
                                         res_n, res_e, node_out, edge_out);
}

// Round 2
// 686.056 us; speedup vs baseline: 1.6580x; 1.1445x over previous
//
#include <hip/hip_runtime.h>

#define DEVINL __device__ __forceinline__

// ---- problem constants (f32 problem) -----------------------------------
#define NLOC 1024
#define NNEI 64
#define NDIM 128
#define EDIM 64
#define ADIM 64
#define ASEL 20

// ---- static device workspace -------------------------------------------
enum : size_t {
  WS_NSELF = 0,                        // [1024,128] silu(node@W_self+b)
  WS_NW0   = WS_NSELF + 1024*128,      // [1024,128] node@W0 + b_ne
  WS_NV0   = WS_NW0   + 1024*128,      // [1024,64]  node@V0 + b_es
  WS_NA1   = WS_NV0   + 1024*64,       // [1024,64]  node@A1 + b_ea1
  WS_NB1   = WS_NA1   + 1024*64,       // [1024,64]  node@B1 + b_as
  WS_PA2   = WS_NB1   + 1024*64,       // [1024,20,64] e_ang @ A2
  WS_PA3   = WS_PA2   + 1024*ASEL*64,  // [1024,20,64] e_ang @ A3
  WS_PB2   = WS_PA3   + 1024*ASEL*64,  // [1024,20,64] e_ang @ B2
  WS_PB3   = WS_PB2   + 1024*ASEL*64,  // [1024,20,64] e_ang @ B3
  WS_F32_END = WS_PB3 + 1024*ASEL*64
};
__device__ float g_ws[WS_F32_END];
__device__ float g_red[1024*ASEL*64];   // reduced (K2 -> K3)

DEVINL float siluf(float x) {
  return x * __builtin_amdgcn_rcpf(1.0f + __expf(-x));
}

// =========================================================================
// K0: per-node projections. grid=1024 x 128.
// =========================================================================
__global__ __launch_bounds__(128) void k0_node_pre(
    const float* __restrict__ node,
    const float* __restrict__ W_self, const float* __restrict__ b_self,
    const float* __restrict__ W_ne,   const float* __restrict__ b_ne,
    const float* __restrict__ W_es,   const float* __restrict__ b_es,
    const float* __restrict__ W_ea1,  const float* __restrict__ b_ea1,
    const float* __restrict__ W_as,   const float* __restrict__ b_as)
{
  const int l = blockIdx.x, t = threadIdx.x;
  __shared__ float nl[128];
  nl[t] = node[l*128 + t];
  __syncthreads();
  float aS = b_self[t];
  float aW = b_ne[t];
  #pragma unroll 8
  for (int k = 0; k < 128; ++k) {
    float nv = nl[k];
    aS = fmaf(nv, W_self[k*128 + t], aS);
    aW = fmaf(nv, W_ne[k*128 + t], aW);
  }
  g_ws[WS_NSELF + l*128 + t] = siluf(aS);
  g_ws[WS_NW0   + l*128 + t] = aW;
  if (t < 64) {
    float aV = b_es[t], aA = b_ea1[t], aB = b_as[t];
    #pragma unroll 8
    for (int k = 0; k < 128; ++k) {
      float nv = nl[k];
      aV = fmaf(nv, W_es[k*64 + t], aV);
      aA = fmaf(nv, W_ea1[(64 + k)*64 + t], aA);
      aB = fmaf(nv, W_as[(64 + k)*64 + t], aB);
    }
    g_ws[WS_NV0 + l*64 + t] = aV;
    g_ws[WS_NA1 + l*64 + t] = aA;
    g_ws[WS_NB1 + l*64 + t] = aB;
  }
}

// =========================================================================
// KP: e_ang projections -> global.  grid=1024 x 256.
//   projM[l,j,c] = sum_k e_ang[l,j,k] * M[k,c],  M in {A2,A3,B2,B3}.
// =========================================================================
__global__ __launch_bounds__(256) void kp_proj(
    const float* __restrict__ edge,
    const float* __restrict__ W_ea1, const float* __restrict__ W_as)
{
  const int l = blockIdx.x, t = threadIdx.x;
  __shared__ float eang[ASEL*65];
  for (int e = t; e < ASEL*64; e += 256)
    eang[(e >> 6)*65 + (e & 63)] = edge[(size_t)l*4096 + e];
  __syncthreads();
  const int o = t & 63, wv = t >> 6;
  #pragma unroll 1
  for (int m = 0; m < 4; ++m) {
    const float* __restrict__ Wp =
          (m == 0) ? (W_ea1 + 192*64)
        : (m == 1) ? (W_ea1 + 256*64)
        : (m == 2) ? (W_as  + 192*64)
        :            (W_as  + 256*64);
    float* __restrict__ outp = g_ws +
          ((m == 0) ? WS_PA2 : (m == 1) ? WS_PA3 : (m == 2) ? WS_PB2 : WS_PB3)
        + (size_t)l*ASEL*64;
    float a0 = 0.f, a1 = 0.f, a2 = 0.f, a3 = 0.f, a4 = 0.f;
    #pragma unroll 4
    for (int k = 0; k < 64; ++k) {
      float w = Wp[k*64 + o];
      a0 = fmaf(eang[(wv     )*65 + k], w, a0);
      a1 = fmaf(eang[(wv +  4)*65 + k], w, a1);
      a2 = fmaf(eang[(wv +  8)*65 + k], w, a2);
      a3 = fmaf(eang[(wv + 12)*65 + k], w, a3);
      a4 = fmaf(eang[(wv + 16)*65 + k], w, a4);
    }
    outp[(wv     )*64 + o] = a0;
    outp[(wv +  4)*64 + o] = a1;
    outp[(wv +  8)*64 + o] = a2;
    outp[(wv + 12)*64 + o] = a3;
    outp[(wv + 16)*64 + o] = a4;
  }
}

// =========================================================================
// K2: angle kernel. grid = 1024*5, block 256, 4 blocks/CU.
//   Block (l, b) handles 80 rows = i-groups 4b..4b+3 of pair-matrix (i,j).
//   Single LDS stage, ONE barrier. Thread tile 5 rows x 4 cols, rows share
//   one i; wave w == i-group 4b+w  ->  j-reduction = register accum +
//   shfl_xor(16,32), g_red written from lane<16. Zero atomics.
//   A0/B0 weights read from global (L1/L2-resident, uniform across rg).
// =========================================================================
__global__ __launch_bounds__(256, 4) void k2_angle(
    const float* __restrict__ ang,
    const float* __restrict__ a_sw,
    const float* __restrict__ res_a,
    const float* __restrict__ W_ea1, const float* __restrict__ W_as,
    float* __restrict__ angle_out)
{
  const int bid = blockIdx.x;
  const int l = bid / 5, b = bid % 5;
  const int t = threadIdx.x;

  __shared__ __align__(16) float angl[80*68];               // 21.8 KB
  __shared__ __align__(16) float eA2l[ASEL*68], eB2l[ASEL*68]; // 10.9 KB
  __shared__ float aswl[ASEL];

  // ---- stage 80 angle rows, coalesced float4 ---------------------------
  const float* __restrict__ angbase = ang + ((size_t)l*400 + b*80)*64;
  #pragma unroll
  for (int q = 0; q < 5; ++q) {
    int g = t + q*256;                 // float4 index 0..1279
    int lr = g >> 4, c4 = g & 15;
    float4 v = reinterpret_cast<const float4*>(angbase)[g];
    *reinterpret_cast<float4*>(&angl[lr*68 + c4*4]) = v;
  }
  // ---- stage eA2/eB2 (all 20 j rows) -----------------------------------
  {
    const float* __restrict__ pa2 = g_ws + WS_PA2 + (size_t)l*ASEL*64;
    const float* __restrict__ pb2 = g_ws + WS_PB2 + (size_t)l*ASEL*64;
    for (int g = t; g < ASEL*16; g += 256) {   // 320 float4 per mat
      int j = g >> 4, c4 = g & 15;
      *reinterpret_cast<float4*>(&eA2l[j*68 + c4*4]) =
          reinterpret_cast<const float4*>(pa2)[g];
      *reinterpret_cast<float4*>(&eB2l[j*68 + c4*4]) =
          reinterpret_cast<const float4*>(pb2)[g];
    }
  }
  if (t < ASEL) aswl[t] = a_sw[l*ASEL + t];

  const int cg = t & 15, rg = t >> 4;
  const int c0 = cg*4;
  const int i_loc = rg >> 2;           // 0..3 == wave index
  const int i = b*4 + i_loc;           // global i 0..19
  const int lr0 = rg*5;                // local row base

  // per-thread broadcast vectors (registers; i, c0 fixed per thread)
  float4 nA1v = *reinterpret_cast<const float4*>(g_ws + WS_NA1 + l*64 + c0);
  float4 nB1v = *reinterpret_cast<const float4*>(g_ws + WS_NB1 + l*64 + c0);
  float4 eA3v = *reinterpret_cast<const float4*>(g_ws + WS_PA3 + ((size_t)l*ASEL + i)*64 + c0);
  float4 eB3v = *reinterpret_cast<const float4*>(g_ws + WS_PB3 + ((size_t)l*ASEL + i)*64 + c0);
  float4 resav = *reinterpret_cast<const float4*>(res_a + c0);

  __syncthreads();                     // the only barrier

  const float* __restrict__ A0g = W_ea1;   // rows 0..63 = A0, [k][c]
  const float* __restrict__ B0g = W_as;    // rows 0..63 = B0

  float accA[20], accB[20];
  #pragma unroll
  for (int q = 0; q < 20; ++q) { accA[q] = 0.f; accB[q] = 0.f; }

  #pragma unroll 2
  for (int k = 0; k < 64; k += 4) {
    float vr[5][4];
    #pragma unroll
    for (int q = 0; q < 5; ++q)
      *reinterpret_cast<float4*>(vr[q]) =
          *reinterpret_cast<const float4*>(&angl[(lr0 + q)*68 + k]);
    #pragma unroll
    for (int kk = 0; kk < 4; ++kk) {
      float4 wA = *reinterpret_cast<const float4*>(A0g + (size_t)(k + kk)*64 + c0);
      float4 wB = *reinterpret_cast<const float4*>(B0g + (size_t)(k + kk)*64 + c0);
      #pragma unroll
      for (int q = 0; q < 5; ++q) {
        float av = vr[q][kk];
        accA[q*4+0] = fmaf(av, wA.x, accA[q*4+0]);
        accA[q*4+1] = fmaf(av, wA.y, accA[q*4+1]);
        accA[q*4+2] = fmaf(av, wA.z, accA[q*4+2]);
        accA[q*4+3] = fmaf(av, wA.w, accA[q*4+3]);
        accB[q*4+0] = fmaf(av, wB.x, accB[q*4+0]);
        accB[q*4+1] = fmaf(av, wB.y, accB[q*4+1]);
        accB[q*4+2] = fmaf(av, wB.z, accB[q*4+2]);
        accB[q*4+3] = fmaf(av, wB.w, accB[q*4+3]);
      }
    }
  }

  // ---- epilogue: silu, residual write, register j-reduction ------------
  float red0 = 0.f, red1 = 0.f, red2 = 0.f, red3 = 0.f;
  #pragma unroll
  for (int q = 0; q < 5; ++q) {
    int lr = lr0 + q;
    int j = lr - i_loc*20;             // 0..19
    float aswj = aswl[j];
    float4 e2A = *reinterpret_cast<const float4*>(&eA2l[j*68 + c0]);
    float4 e2B = *reinterpret_cast<const float4*>(&eB2l[j*68 + c0]);
    float4 orig = *reinterpret_cast<const float4*>(&angl[lr*68 + c0]);

    float pA0 = accA[q*4+0] + nA1v.x + e2A.x + eA3v.x;
    float pA1 = accA[q*4+1] + nA1v.y + e2A.y + eA3v.y;
    float pA2 = accA[q*4+2] + nA1v.z + e2A.z + eA3v.z;
    float pA3 = accA[q*4+3] + nA1v.w + e2A.w + eA3v.w;
    red0 = fmaf(aswj, siluf(pA0), red0);
    red1 = fmaf(aswj, siluf(pA1), red1);
    red2 = fmaf(aswj, siluf(pA2), red2);
    red3 = fmaf(aswj, siluf(pA3), red3);

    float pB0 = accB[q*4+0] + nB1v.x + e2B.x + eB3v.x;
    float pB1 = accB[q*4+1] + nB1v.y + e2B.y + eB3v.y;
    float pB2 = accB[q*4+2] + nB1v.z + e2B.z + eB3v.z;
    float pB3 = accB[q*4+3] + nB1v.w + e2B.w + eB3v.w;
    float4 outv;
    outv.x = orig.x + resav.x * siluf(pB0);
    outv.y = orig.y + resav.y * siluf(pB1);
    outv.z = orig.z + resav.z * siluf(pB2);
    outv.w = orig.w + resav.w * siluf(pB3);
    *reinterpret_cast<float4*>(angle_out + ((size_t)l*400 + b*80 + lr)*64 + c0) = outv;
  }

  // cross-thread j-reduction: lanes {cg, cg+16, cg+32, cg+48} share (i, c0)
  red0 += __shfl_xor(red0, 16); red0 += __shfl_xor(red0, 32);
  red1 += __shfl_xor(red1, 16); red1 += __shfl_xor(red1, 32);
  red2 += __shfl_xor(red2, 16); red2 += __shfl_xor(red2, 32);
  red3 += __shfl_xor(red3, 16); red3 += __shfl_xor(red3, 32);
  if ((t & 0x30) == 0) {               // rg % 4 == 0 -> 16 lanes per wave
    float sc = aswl[i] * 0.22360679775f;   // asw[i] / sqrt(20)
    float4 o4 = make_float4(red0*sc, red1*sc, red2*sc, red3*sc);
    *reinterpret_cast<float4*>(g_red + ((size_t)l*ASEL + i)*64 + c0) = o4;
  }
}

// =========================================================================
// K3: node + edge kernel. grid=1024 x 256.
// =========================================================================
__global__ __launch_bounds__(256) void k3_node_edge(
    const float* __restrict__ node_ext,
    const float* __restrict__ edge,
    const float* __restrict__ h2,
    const float* __restrict__ sw,
    const int* __restrict__ nlist,
    const float* __restrict__ W_sym, const float* __restrict__ b_sym,
    const float* __restrict__ W_ne,  const float* __restrict__ W_es,
    const float* __restrict__ W_ea2, const float* __restrict__ b_ea2,
    const float* __restrict__ res_n, const float* __restrict__ res_e,
    float* __restrict__ node_out,
    float* __restrict__ edge_out)
{
  const int l = blockIdx.x, t = threadIdx.x;
  __shared__ float Ef[64*64];
  __shared__ float Nf[64*128];
  __shared__ float hwv[64*4];
  __shared__ float swl[64];
  __shared__ float hgE[3*64], hgN[3*128];
  __shared__ float cat[768];
  __shared__ float nsym[128];
  __shared__ float msgl[ASEL*64];
  __shared__ float msgc[64];

  for (int e = t; e < 4096; e += 256) Ef[e] = edge[l*4096 + e];
  for (int e = t; e < 8192; e += 256) {
    int n = e >> 7, k = e & 127;
    int idx = nlist[l*64 + n];
    Nf[e] = node_ext[(size_t)idx*128 + k];
  }
  if (t < 64) {
    float s = sw[l*64 + t];
    swl[t] = s;
    hwv[t*4+0] = h2[(l*64 + t)*3 + 0] * s;
    hwv[t*4+1] = h2[(l*64 + t)*3 + 1] * s;
    hwv[t*4+2] = h2[(l*64 + t)*3 + 2] * s;
  }
  __syncthreads();

  // hg = (h2*sw)^T @ G / 64
  for (int e = t; e < 192; e += 256) {
    int tt = e >> 6, d = e & 63;
    float acc = 0.f;
    #pragma unroll 4
    for (int n = 0; n < 64; ++n) acc = fmaf(hwv[n*4 + tt], Ef[n*64 + d], acc);
    hgE[tt*64 + d] = acc * (1.f/64.f);
  }
  for (int e = t; e < 384; e += 256) {
    int tt = e >> 7, k = e & 127;
    float acc = 0.f;
    #pragma unroll 4
    for (int n = 0; n < 64; ++n) acc = fmaf(hwv[n*4 + tt], Nf[n*128 + k], acc);
    hgN[tt*128 + k] = acc * (1.f/64.f);
  }
  __syncthreads();

  // cat = [grrg(edge)(4x64), grrg(nei)(4x128)]
  for (int e = t; e < 256; e += 256) {
    int a = e >> 6, d = e & 63;
    cat[e] = (hgE[a]*hgE[d] + hgE[64 + a]*hgE[64 + d] + hgE[128 + a]*hgE[128 + d]) * (1.f/3.f);
  }
  for (int e = t; e < 512; e += 256) {
    int a = e >> 7, k = e & 127;
    cat[256 + e] = (hgN[a]*hgN[k] + hgN[128 + a]*hgN[128 + k] + hgN[256 + a]*hgN[256 + k]) * (1.f/3.f);
  }
  __syncthreads();

  // node_sym (threads 0-127) and e_angle_msg (threads 128-255)
  if (t < 128) {
    float acc = b_sym[t];
    #pragma unroll 4
    for (int c = 0; c < 768; ++c)
      acc = fmaf(cat[c], W_sym[c*128 + t], acc);
    nsym[t] = siluf(acc);
  } else {
    int idx = t - 128;
    if (idx < 64) msgc[idx] = siluf(b_ea2[idx]);
    for (int q = 0; q < 10; ++q) {
      int e = q*128 + idx;
      int n = e >> 6, oo = e & 63;
      float acc = b_ea2[oo];
      #pragma unroll 4
      for (int k = 0; k < 64; ++k)
        acc = fmaf(g_red[(l*ASEL + n)*64 + k], W_ea2[k*64 + oo], acc);
      msgl[e] = siluf(acc);
    }
  }
  __syncthreads();

  // main GEMM: 64 nei-rows x (128 ne-cols + 64 es-cols)
  if (t < 128) {
    const int c = t;
    float colbase = g_ws[WS_NW0 + l*128 + c];
    float nedge = 0.f;
    for (int nt4 = 0; nt4 < 4; ++nt4) {
      float acc[16];
      #pragma unroll
      for (int nn = 0; nn < 16; ++nn) acc[nn] = colbase;
      #pragma unroll 4
      for (int k = 0; k < 128; ++k) {
        float w = W_ne[(128 + k)*128 + c];
        #pragma unroll
        for (int nn = 0; nn < 16; ++nn)
          acc[nn] = fmaf(Nf[(nt4*16 + nn)*128 + k], w, acc[nn]);
      }
      #pragma unroll 4
      for (int k = 0; k < 64; ++k) {
        float w = W_ne[(256 + k)*128 + c];
        #pragma unroll
        for (int nn = 0; nn < 16; ++nn)
          acc[nn] = fmaf(Ef[(nt4*16 + nn)*64 + k], w, acc[nn]);
      }
      #pragma unroll
      for (int nn = 0; nn < 16; ++nn)
        nedge = fmaf(siluf(acc[nn]), swl[nt4*16 + nn], nedge);
    }
    nedge *= (1.f/64.f);
    float nodev = node_ext[l*128 + c];
    float outv = nodev + res_n[c]*g_ws[WS_NSELF + l*128 + c]
               + res_n[128 + c]*nsym[c] + res_n[256 + c]*nedge;
    node_out[l*128 + c] = outv;
  } else if (t < 192) {
    const int o = t - 128;
    float colbase = g_ws[WS_NV0 + l*64 + o];
    float re0 = res_e[o], re1 = res_e[64 + o];
    float msgcv = msgc[o];
    for (int nt4 = 0; nt4 < 4; ++nt4) {
      float acc[16];
      #pragma unroll
      for (int nn = 0; nn < 16; ++nn) acc[nn] = colbase;
      #pragma unroll 4
      for (int k = 0; k < 128; ++k) {
        float w = W_es[(128 + k)*64 + o];
        #pragma unroll
        for (int nn = 0; nn < 16; ++nn)
          acc[nn] = fmaf(Nf[(nt4*16 + nn)*128 + k], w, acc[nn]);
      }
      #pragma unroll 4
      for (int k = 0; k < 64; ++k) {
        float w = W_es[(256 + k)*64 + o];
        #pragma unroll
        for (int nn = 0; nn < 16; ++nn)
          acc[nn] = fmaf(Ef[(nt4*16 + nn)*64 + k], w, acc[nn]);
      }
      #pragma unroll
      for (int nn = 0; nn < 16; ++nn) {
        int n = nt4*16 + nn;
        float s = siluf(acc[nn]);
        float msgv = (n < ASEL) ? msgl[n*64 + o] : msgcv;
        edge_out[(size_t)l*4096 + n*64 + o] = Ef[n*64 + o] + re0*s + re1*msgv;
      }
    }
  }
}

// =========================================================================
extern "C" void kernel_launch(void* const* d_in, const int* in_sizes, int n_in,
                              void* d_out, int out_size, void* d_ws, size_t ws_size,
                              hipStream_t stream) {
  const float* node_ext = (const float*)d_in[0];
  const float* edge_ebd = (const float*)d_in[1];
  const float* h2       = (const float*)d_in[2];
  const float* angle    = (const float*)d_in[3];
  const float* sw       = (const float*)d_in[4];
  const float* a_sw     = (const float*)d_in[5];
  const float* W_self   = (const float*)d_in[6];
  const float* b_self   = (const float*)d_in[7];
  const float* W_sym    = (const float*)d_in[8];
  const float* b_sym    = (const float*)d_in[9];
  const float* W_ne     = (const float*)d_in[10];
  const float* b_ne     = (const float*)d_in[11];
  const float* W_es     = (const float*)d_in[12];
  const float* b_es     = (const float*)d_in[13];
  const float* W_ea1    = (const float*)d_in[14];
  const float* b_ea1    = (const float*)d_in[15];
  const float* W_ea2    = (const float*)d_in[16];
  const float* b_ea2    = (const float*)d_in[17];
  const float* W_as     = (const float*)d_in[18];
  const float* b_as     = (const float*)d_in[19];
  const float* res_n    = (const float*)d_in[20];
  const float* res_e    = (const float*)d_in[21];
  const float* res_a    = (const float*)d_in[22];
  const int*   nlist    = (const int*)d_in[23];

  float* out = (float*)d_out;
  float* node_out  = out;
  float* edge_out  = out + 1024*128;
  float* angle_out = out + 1024*128 + (size_t)1024*64*64;

  k0_node_pre<<<1024, 128, 0, stream>>>(node_ext, W_self, b_self, W_ne, b_ne,
                                        W_es, b_es, W_ea1, b_ea1, W_as, b_as);
  kp_proj<<<1024, 256, 0, stream>>>(edge_ebd, W_ea1, W_as);
  k2_angle<<<1024*5, 256, 0, stream>>>(angle, a_sw, res_a,
                                       W_ea1, W_as, angle_out);
  k3_node_edge<<<1024, 256, 0, stream>>>(node_ext, edge_ebd, h2, sw, nlist,
                                         W_sym, b_sym, W_ne, W_es, W_ea2, b_ea2,
                                         res_n, res_e, node_out, edge_out);
}

// Round 3
// 653.005 us; speedup vs baseline: 1.7419x; 1.0506x over previous
//
#include <hip/hip_runtime.h>

#define DEVINL __device__ __forceinline__

// ---- problem constants (f32 problem) -----------------------------------
#define NLOC 1024
#define NNEI 64
#define NDIM 128
#define EDIM 64
#define ADIM 64
#define ASEL 20

// ---- static device workspace -------------------------------------------
enum : size_t {
  WS_NSELF = 0,                        // [1024,128] silu(node@W_self+b)
  WS_NW0   = WS_NSELF + 1024*128,      // [1024,128] node@W0 + b_ne
  WS_NV0   = WS_NW0   + 1024*128,      // [1024,64]  node@V0 + b_es
  WS_NA1   = WS_NV0   + 1024*64,       // [1024,64]  node@A1 + b_ea1
  WS_NB1   = WS_NA1   + 1024*64,       // [1024,64]  node@B1 + b_as
  WS_PA2   = WS_NB1   + 1024*64,       // [1024,20,64] e_ang @ A2
  WS_PA3   = WS_PA2   + 1024*ASEL*64,  // [1024,20,64] e_ang @ A3
  WS_PB2   = WS_PA3   + 1024*ASEL*64,  // [1024,20,64] e_ang @ B2
  WS_PB3   = WS_PB2   + 1024*ASEL*64,  // [1024,20,64] e_ang @ B3
  WS_F32_END = WS_PB3 + 1024*ASEL*64
};
__device__ float g_ws[WS_F32_END];
__device__ float g_red[1024*ASEL*64];   // reduced (K2 -> K3)

DEVINL float siluf(float x) {
  return x * __builtin_amdgcn_rcpf(1.0f + __expf(-x));
}

// =========================================================================
// K0: per-node projections. grid=1024 x 128.
// =========================================================================
__global__ __launch_bounds__(128) void k0_node_pre(
    const float* __restrict__ node,
    const float* __restrict__ W_self, const float* __restrict__ b_self,
    const float* __restrict__ W_ne,   const float* __restrict__ b_ne,
    const float* __restrict__ W_es,   const float* __restrict__ b_es,
    const float* __restrict__ W_ea1,  const float* __restrict__ b_ea1,
    const float* __restrict__ W_as,   const float* __restrict__ b_as)
{
  const int l = blockIdx.x, t = threadIdx.x;
  __shared__ float nl[128];
  nl[t] = node[l*128 + t];
  __syncthreads();
  float aS = b_self[t];
  float aW = b_ne[t];
  #pragma unroll 8
  for (int k = 0; k < 128; ++k) {
    float nv = nl[k];
    aS = fmaf(nv, W_self[k*128 + t], aS);
    aW = fmaf(nv, W_ne[k*128 + t], aW);
  }
  g_ws[WS_NSELF + l*128 + t] = siluf(aS);
  g_ws[WS_NW0   + l*128 + t] = aW;
  if (t < 64) {
    float aV = b_es[t], aA = b_ea1[t], aB = b_as[t];
    #pragma unroll 8
    for (int k = 0; k < 128; ++k) {
      float nv = nl[k];
      aV = fmaf(nv, W_es[k*64 + t], aV);
      aA = fmaf(nv, W_ea1[(64 + k)*64 + t], aA);
      aB = fmaf(nv, W_as[(64 + k)*64 + t], aB);
    }
    g_ws[WS_NV0 + l*64 + t] = aV;
    g_ws[WS_NA1 + l*64 + t] = aA;
    g_ws[WS_NB1 + l*64 + t] = aB;
  }
}

// =========================================================================
// KP: e_ang projections -> global.  grid=1024 x 256.
// =========================================================================
__global__ __launch_bounds__(256) void kp_proj(
    const float* __restrict__ edge,
    const float* __restrict__ W_ea1, const float* __restrict__ W_as)
{
  const int l = blockIdx.x, t = threadIdx.x;
  __shared__ float eang[ASEL*65];
  for (int e = t; e < ASEL*64; e += 256)
    eang[(e >> 6)*65 + (e & 63)] = edge[(size_t)l*4096 + e];
  __syncthreads();
  const int o = t & 63, wv = t >> 6;
  #pragma unroll 1
  for (int m = 0; m < 4; ++m) {
    const float* __restrict__ Wp =
          (m == 0) ? (W_ea1 + 192*64)
        : (m == 1) ? (W_ea1 + 256*64)
        : (m == 2) ? (W_as  + 192*64)
        :            (W_as  + 256*64);
    float* __restrict__ outp = g_ws +
          ((m == 0) ? WS_PA2 : (m == 1) ? WS_PA3 : (m == 2) ? WS_PB2 : WS_PB3)
        + (size_t)l*ASEL*64;
    float a0 = 0.f, a1 = 0.f, a2 = 0.f, a3 = 0.f, a4 = 0.f;
    #pragma unroll 4
    for (int k = 0; k < 64; ++k) {
      float w = Wp[k*64 + o];
      a0 = fmaf(eang[(wv     )*65 + k], w, a0);
      a1 = fmaf(eang[(wv +  4)*65 + k], w, a1);
      a2 = fmaf(eang[(wv +  8)*65 + k], w, a2);
      a3 = fmaf(eang[(wv + 12)*65 + k], w, a3);
      a4 = fmaf(eang[(wv + 16)*65 + k], w, a4);
    }
    outp[(wv     )*64 + o] = a0;
    outp[(wv +  4)*64 + o] = a1;
    outp[(wv +  8)*64 + o] = a2;
    outp[(wv + 12)*64 + o] = a3;
    outp[(wv + 16)*64 + o] = a4;
  }
}

// =========================================================================
// K2: angle kernel. grid = 1024*5, block 256, 4 blocks/CU.
// =========================================================================
__global__ __launch_bounds__(256, 4) void k2_angle(
    const float* __restrict__ ang,
    const float* __restrict__ a_sw,
    const float* __restrict__ res_a,
    const float* __restrict__ W_ea1, const float* __restrict__ W_as,
    float* __restrict__ angle_out)
{
  const int bid = blockIdx.x;
  const int l = bid / 5, b = bid % 5;
  const int t = threadIdx.x;

  __shared__ __align__(16) float angl[80*68];               // 21.8 KB
  __shared__ __align__(16) float eA2l[ASEL*68], eB2l[ASEL*68]; // 10.9 KB
  __shared__ float aswl[ASEL];

  const float* __restrict__ angbase = ang + ((size_t)l*400 + b*80)*64;
  #pragma unroll
  for (int q = 0; q < 5; ++q) {
    int g = t + q*256;                 // float4 index 0..1279
    int lr = g >> 4, c4 = g & 15;
    float4 v = reinterpret_cast<const float4*>(angbase)[g];
    *reinterpret_cast<float4*>(&angl[lr*68 + c4*4]) = v;
  }
  {
    const float* __restrict__ pa2 = g_ws + WS_PA2 + (size_t)l*ASEL*64;
    const float* __restrict__ pb2 = g_ws + WS_PB2 + (size_t)l*ASEL*64;
    for (int g = t; g < ASEL*16; g += 256) {   // 320 float4 per mat
      int j = g >> 4, c4 = g & 15;
      *reinterpret_cast<float4*>(&eA2l[j*68 + c4*4]) =
          reinterpret_cast<const float4*>(pa2)[g];
      *reinterpret_cast<float4*>(&eB2l[j*68 + c4*4]) =
          reinterpret_cast<const float4*>(pb2)[g];
    }
  }
  if (t < ASEL) aswl[t] = a_sw[l*ASEL + t];

  const int cg = t & 15, rg = t >> 4;
  const int c0 = cg*4;
  const int i_loc = rg >> 2;           // 0..3 == wave index
  const int i = b*4 + i_loc;           // global i 0..19
  const int lr0 = rg*5;                // local row base

  float4 nA1v = *reinterpret_cast<const float4*>(g_ws + WS_NA1 + l*64 + c0);
  float4 nB1v = *reinterpret_cast<const float4*>(g_ws + WS_NB1 + l*64 + c0);
  float4 eA3v = *reinterpret_cast<const float4*>(g_ws + WS_PA3 + ((size_t)l*ASEL + i)*64 + c0);
  float4 eB3v = *reinterpret_cast<const float4*>(g_ws + WS_PB3 + ((size_t)l*ASEL + i)*64 + c0);
  float4 resav = *reinterpret_cast<const float4*>(res_a + c0);

  __syncthreads();                     // the only barrier

  const float* __restrict__ A0g = W_ea1;   // rows 0..63 = A0, [k][c]
  const float* __restrict__ B0g = W_as;    // rows 0..63 = B0

  float accA[20], accB[20];
  #pragma unroll
  for (int q = 0; q < 20; ++q) { accA[q] = 0.f; accB[q] = 0.f; }

  #pragma unroll 2
  for (int k = 0; k < 64; k += 4) {
    float vr[5][4];
    #pragma unroll
    for (int q = 0; q < 5; ++q)
      *reinterpret_cast<float4*>(vr[q]) =
          *reinterpret_cast<const float4*>(&angl[(lr0 + q)*68 + k]);
    #pragma unroll
    for (int kk = 0; kk < 4; ++kk) {
      float4 wA = *reinterpret_cast<const float4*>(A0g + (size_t)(k + kk)*64 + c0);
      float4 wB = *reinterpret_cast<const float4*>(B0g + (size_t)(k + kk)*64 + c0);
      #pragma unroll
      for (int q = 0; q < 5; ++q) {
        float av = vr[q][kk];
        accA[q*4+0] = fmaf(av, wA.x, accA[q*4+0]);
        accA[q*4+1] = fmaf(av, wA.y, accA[q*4+1]);
        accA[q*4+2] = fmaf(av, wA.z, accA[q*4+2]);
        accA[q*4+3] = fmaf(av, wA.w, accA[q*4+3]);
        accB[q*4+0] = fmaf(av, wB.x, accB[q*4+0]);
        accB[q*4+1] = fmaf(av, wB.y, accB[q*4+1]);
        accB[q*4+2] = fmaf(av, wB.z, accB[q*4+2]);
        accB[q*4+3] = fmaf(av, wB.w, accB[q*4+3]);
      }
    }
  }

  float red0 = 0.f, red1 = 0.f, red2 = 0.f, red3 = 0.f;
  #pragma unroll
  for (int q = 0; q < 5; ++q) {
    int lr = lr0 + q;
    int j = lr - i_loc*20;             // 0..19
    float aswj = aswl[j];
    float4 e2A = *reinterpret_cast<const float4*>(&eA2l[j*68 + c0]);
    float4 e2B = *reinterpret_cast<const float4*>(&eB2l[j*68 + c0]);
    float4 orig = *reinterpret_cast<const float4*>(&angl[lr*68 + c0]);

    float pA0 = accA[q*4+0] + nA1v.x + e2A.x + eA3v.x;
    float pA1 = accA[q*4+1] + nA1v.y + e2A.y + eA3v.y;
    float pA2 = accA[q*4+2] + nA1v.z + e2A.z + eA3v.z;
    float pA3 = accA[q*4+3] + nA1v.w + e2A.w + eA3v.w;
    red0 = fmaf(aswj, siluf(pA0), red0);
    red1 = fmaf(aswj, siluf(pA1), red1);
    red2 = fmaf(aswj, siluf(pA2), red2);
    red3 = fmaf(aswj, siluf(pA3), red3);

    float pB0 = accB[q*4+0] + nB1v.x + e2B.x + eB3v.x;
    float pB1 = accB[q*4+1] + nB1v.y + e2B.y + eB3v.y;
    float pB2 = accB[q*4+2] + nB1v.z + e2B.z + eB3v.z;
    float pB3 = accB[q*4+3] + nB1v.w + e2B.w + eB3v.w;
    float4 outv;
    outv.x = orig.x + resav.x * siluf(pB0);
    outv.y = orig.y + resav.y * siluf(pB1);
    outv.z = orig.z + resav.z * siluf(pB2);
    outv.w = orig.w + resav.w * siluf(pB3);
    *reinterpret_cast<float4*>(angle_out + ((size_t)l*400 + b*80 + lr)*64 + c0) = outv;
  }

  red0 += __shfl_xor(red0, 16); red0 += __shfl_xor(red0, 32);
  red1 += __shfl_xor(red1, 16); red1 += __shfl_xor(red1, 32);
  red2 += __shfl_xor(red2, 16); red2 += __shfl_xor(red2, 32);
  red3 += __shfl_xor(red3, 16); red3 += __shfl_xor(red3, 32);
  if ((t & 0x30) == 0) {
    float sc = aswl[i] * 0.22360679775f;   // asw[i] / sqrt(20)
    float4 o4 = make_float4(red0*sc, red1*sc, red2*sc, red3*sc);
    *reinterpret_cast<float4*>(g_red + ((size_t)l*ASEL + i)*64 + c0) = o4;
  }
}

// =========================================================================
// K3: node + edge kernel. grid=1024 x 256, 2 blocks/CU.
//   Main phase is ONE register-tiled GEMM: C[64x192] = AL[64x192] @ W[192x192]
//   AL = [Nf | Ef] in LDS (stride 196). W rows 128+k of W_ne / W_es, staged
//   in K-chunks of 16 (12 KB LDS) with register prefetch of the next chunk.
//   Thread (ty,tx): 4 rows x 12 cols, 48 accumulators, float4 LDS reads.
//   Epilogue: es-cols -> edge_out directly; ne-cols -> shfl+LDS-atomic
//   n-reduction -> node_out.
// =========================================================================
__global__ __launch_bounds__(256, 2) void k3_node_edge(
    const float* __restrict__ node_ext,
    const float* __restrict__ edge,
    const float* __restrict__ h2,
    const float* __restrict__ sw,
    const int* __restrict__ nlist,
    const float* __restrict__ W_sym, const float* __restrict__ b_sym,
    const float* __restrict__ W_ne,  const float* __restrict__ W_es,
    const float* __restrict__ W_ea2, const float* __restrict__ b_ea2,
    const float* __restrict__ res_n, const float* __restrict__ res_e,
    float* __restrict__ node_out,
    float* __restrict__ edge_out)
{
  const int l = blockIdx.x, t = threadIdx.x;
  __shared__ __align__(16) float AL[64*196];   // 50.2 KB: [n][k<128 Nf | 128+o Ef]
  __shared__ __align__(16) float WL[16*192];   // 12 KB weight chunk [kk][c]
  __shared__ float hwv[64*4];
  __shared__ float swl[64];
  __shared__ float hgE[3*64], hgN[3*128];
  __shared__ float cat[768];
  __shared__ float nsym[128];
  __shared__ float msgl[ASEL*64];
  __shared__ float msgc[64];
  __shared__ float redn[128];
  __shared__ int   idxl[64];

  if (t < 64) idxl[t] = nlist[l*64 + t];
  if (t >= 64 && t < 192) redn[t - 64] = 0.f;
  if (t < 64) {
    float s = sw[l*64 + t];
    swl[t] = s;
    hwv[t*4+0] = h2[(l*64 + t)*3 + 0] * s;
    hwv[t*4+1] = h2[(l*64 + t)*3 + 1] * s;
    hwv[t*4+2] = h2[(l*64 + t)*3 + 2] * s;
  }
  __syncthreads();   // idxl ready

  // ---- stage AL: Nf gather (2048 float4) + Ef (1024 float4) ------------
  for (int g = t; g < 2048; g += 256) {
    int n = g >> 5, q = g & 31;
    float4 v = *reinterpret_cast<const float4*>(node_ext + (size_t)idxl[n]*128 + q*4);
    *reinterpret_cast<float4*>(&AL[n*196 + q*4]) = v;
  }
  for (int g = t; g < 1024; g += 256) {
    int n = g >> 4, q = g & 15;
    float4 v = *reinterpret_cast<const float4*>(edge + (size_t)l*4096 + n*64 + q*4);
    *reinterpret_cast<float4*>(&AL[n*196 + 128 + q*4]) = v;
  }
  __syncthreads();

  // ---- hg = (h2*sw)^T @ [Ef, Nf] / 64 ----------------------------------
  for (int e = t; e < 192; e += 256) {
    int tt = e >> 6, d = e & 63;
    float acc = 0.f;
    #pragma unroll 4
    for (int n = 0; n < 64; ++n) acc = fmaf(hwv[n*4 + tt], AL[n*196 + 128 + d], acc);
    hgE[tt*64 + d] = acc * (1.f/64.f);
  }
  for (int e = t; e < 384; e += 256) {
    int tt = e >> 7, k = e & 127;
    float acc = 0.f;
    #pragma unroll 4
    for (int n = 0; n < 64; ++n) acc = fmaf(hwv[n*4 + tt], AL[n*196 + k], acc);
    hgN[tt*128 + k] = acc * (1.f/64.f);
  }
  __syncthreads();

  // ---- cat = [grrg(edge)(4x64), grrg(nei)(4x128)] ----------------------
  for (int e = t; e < 256; e += 256) {
    int a = e >> 6, d = e & 63;
    cat[e] = (hgE[a]*hgE[d] + hgE[64 + a]*hgE[64 + d] + hgE[128 + a]*hgE[128 + d]) * (1.f/3.f);
  }
  for (int e = t; e < 512; e += 256) {
    int a = e >> 7, k = e & 127;
    cat[256 + e] = (hgN[a]*hgN[k] + hgN[128 + a]*hgN[128 + k] + hgN[256 + a]*hgN[256 + k]) * (1.f/3.f);
  }
  __syncthreads();

  // ---- nsym (threads 0-127) and e_angle_msg (threads 128-255) ----------
  if (t < 128) {
    float acc = b_sym[t];
    #pragma unroll 4
    for (int c = 0; c < 768; ++c)
      acc = fmaf(cat[c], W_sym[c*128 + t], acc);
    nsym[t] = siluf(acc);
  } else {
    int idx = t - 128;
    if (idx < 64) msgc[idx] = siluf(b_ea2[idx]);
    for (int q = 0; q < 10; ++q) {
      int e = q*128 + idx;
      int n = e >> 6, oo = e & 63;
      float acc = b_ea2[oo];
      #pragma unroll 4
      for (int k = 0; k < 64; ++k)
        acc = fmaf(g_red[((size_t)l*ASEL + n)*64 + k], W_ea2[k*64 + oo], acc);
      msgl[e] = siluf(acc);
    }
  }

  // ---- main GEMM: C[64x192] = AL @ W, K-chunks of 16 -------------------
  const int tx = t & 15, ty = t >> 4;
  const int n0 = ty*4, c0 = tx*12;

  float acc[4][12];
  #pragma unroll
  for (int r = 0; r < 4; ++r)
    #pragma unroll
    for (int cc = 0; cc < 12; ++cc) acc[r][cc] = 0.f;

  // prefetch chunk 0 into registers (3 float4 per thread)
  float4 wreg[3];
  #pragma unroll
  for (int q = 0; q < 3; ++q) {
    int g = q*256 + t;                 // 0..767
    int kk = g / 48, c4 = g % 48;
    int c = c4*4, krow = 128 + kk;
    wreg[q] = (c < 128)
        ? *reinterpret_cast<const float4*>(W_ne + (size_t)krow*128 + c)
        : *reinterpret_cast<const float4*>(W_es + (size_t)krow*64 + (c - 128));
  }

  #pragma unroll 1
  for (int kb = 0; kb < 12; ++kb) {
    __syncthreads();                   // WL free (and phase-4 done at kb=0)
    #pragma unroll
    for (int q = 0; q < 3; ++q) {
      int g = q*256 + t;
      int kk = g / 48, c4 = g % 48;
      *reinterpret_cast<float4*>(&WL[kk*192 + c4*4]) = wreg[q];
    }
    if (kb < 11) {                     // issue next-chunk loads early (T14)
      #pragma unroll
      for (int q = 0; q < 3; ++q) {
        int g = q*256 + t;
        int kk = g / 48, c4 = g % 48;
        int c = c4*4, krow = 128 + (kb + 1)*16 + kk;
        wreg[q] = (c < 128)
            ? *reinterpret_cast<const float4*>(W_ne + (size_t)krow*128 + c)
            : *reinterpret_cast<const float4*>(W_es + (size_t)krow*64 + (c - 128));
      }
    }
    __syncthreads();                   // WL ready

    const int kbase = kb*16;
    #pragma unroll
    for (int kk = 0; kk < 16; kk += 4) {
      float ar[4][4];
      #pragma unroll
      for (int r = 0; r < 4; ++r)
        *reinterpret_cast<float4*>(ar[r]) =
            *reinterpret_cast<const float4*>(&AL[(n0 + r)*196 + kbase + kk]);
      #pragma unroll
      for (int j = 0; j < 4; ++j) {
        float4 w0 = *reinterpret_cast<const float4*>(&WL[(kk + j)*192 + c0]);
        float4 w1 = *reinterpret_cast<const float4*>(&WL[(kk + j)*192 + c0 + 4]);
        float4 w2 = *reinterpret_cast<const float4*>(&WL[(kk + j)*192 + c0 + 8]);
        #pragma unroll
        for (int r = 0; r < 4; ++r) {
          float av = ar[r][j];
          acc[r][0]  = fmaf(av, w0.x, acc[r][0]);
          acc[r][1]  = fmaf(av, w0.y, acc[r][1]);
          acc[r][2]  = fmaf(av, w0.z, acc[r][2]);
          acc[r][3]  = fmaf(av, w0.w, acc[r][3]);
          acc[r][4]  = fmaf(av, w1.x, acc[r][4]);
          acc[r][5]  = fmaf(av, w1.y, acc[r][5]);
          acc[r][6]  = fmaf(av, w1.z, acc[r][6]);
          acc[r][7]  = fmaf(av, w1.w, acc[r][7]);
          acc[r][8]  = fmaf(av, w2.x, acc[r][8]);
          acc[r][9]  = fmaf(av, w2.y, acc[r][9]);
          acc[r][10] = fmaf(av, w2.z, acc[r][10]);
          acc[r][11] = fmaf(av, w2.w, acc[r][11]);
        }
      }
    }
  }

  // ---- epilogue --------------------------------------------------------
  float colb[12];
  #pragma unroll
  for (int cc = 0; cc < 12; ++cc) {
    int c = c0 + cc;
    colb[cc] = (c < 128) ? g_ws[WS_NW0 + l*128 + c]
                         : g_ws[WS_NV0 + l*64 + (c - 128)];
  }
  float np[12];
  #pragma unroll
  for (int cc = 0; cc < 12; ++cc) np[cc] = 0.f;

  #pragma unroll
  for (int r = 0; r < 4; ++r) {
    int n = n0 + r;
    float sn = swl[n];
    #pragma unroll
    for (int cc = 0; cc < 12; ++cc) {
      int c = c0 + cc;
      float s = siluf(acc[r][cc] + colb[cc]);
      if (c < 128) {
        np[cc] = fmaf(s, sn, np[cc]);
      } else {
        int o = c - 128;
        float msgv = (n < ASEL) ? msgl[n*64 + o] : msgc[o];
        float ef = AL[n*196 + 128 + o];
        edge_out[(size_t)l*4096 + n*64 + o] =
            ef + res_e[o]*s + res_e[64 + o]*msgv;
      }
    }
  }

  #pragma unroll
  for (int cc = 0; cc < 12; ++cc) {
    np[cc] += __shfl_xor(np[cc], 16);
    np[cc] += __shfl_xor(np[cc], 32);
  }
  if ((ty & 3) == 0) {                 // one lane per (wave, col)
    #pragma unroll
    for (int cc = 0; cc < 12; ++cc) {
      int c = c0 + cc;
      if (c < 128) atomicAdd(&redn[c], np[cc]);
    }
  }
  __syncthreads();

  if (t < 128) {
    const int c = t;
    float nedge = redn[c] * (1.f/64.f);
    float nodev = node_ext[l*128 + c];
    node_out[l*128 + c] = nodev + res_n[c]*g_ws[WS_NSELF + l*128 + c]
                        + res_n[128 + c]*nsym[c] + res_n[256 + c]*nedge;
  }
}

// =========================================================================
extern "C" void kernel_launch(void* const* d_in, const int* in_sizes, int n_in,
                              void* d_out, int out_size, void* d_ws, size_t ws_size,
                              hipStream_t stream) {
  const float* node_ext = (const float*)d_in[0];
  const float* edge_ebd = (const float*)d_in[1];
  const float* h2       = (const float*)d_in[2];
  const float* angle    = (const float*)d_in[3];
  const float* sw       = (const float*)d_in[4];
  const float* a_sw     = (const float*)d_in[5];
  const float* W_self   = (const float*)d_in[6];
  const float* b_self   = (const float*)d_in[7];
  const float* W_sym    = (const float*)d_in[8];
  const float* b_sym    = (const float*)d_in[9];
  const float* W_ne     = (const float*)d_in[10];
  const float* b_ne     = (const float*)d_in[11];
  const float* W_es     = (const float*)d_in[12];
  const float* b_es     = (const float*)d_in[13];
  const float* W_ea1    = (const float*)d_in[14];
  const float* b_ea1    = (const float*)d_in[15];
  const float* W_ea2    = (const float*)d_in[16];
  const float* b_ea2    = (const float*)d_in[17];
  const float* W_as     = (const float*)d_in[18];
  const float* b_as     = (const float*)d_in[19];
  const float* res_n    = (const float*)d_in[20];
  const float* res_e    = (const float*)d_in[21];
  const float* res_a    = (const float*)d_in[22];
  const int*   nlist    = (const int*)d_in[23];

  float* out = (float*)d_out;
  float* node_out  = out;
  float* edge_out  = out + 1024*128;
  float* angle_out = out + 1024*128 + (size_t)1024*64*64;

  k0_node_pre<<<1024, 128, 0, stream>>>(node_ext, W_self, b_self, W_ne, b_ne,
                                        W_es, b_es, W_ea1, b_ea1, W_as, b_as);
  kp_proj<<<1024, 256, 0, stream>>>(edge_ebd, W_ea1, W_as);
  k2_angle<<<1024*5, 256, 0, stream>>>(angle, a_sw, res_a,
                                       W_ea1, W_as, angle_out);
  k3_node_edge<<<1024, 256, 0, stream>>>(node_ext, edge_ebd, h2, sw, nlist,
                                         W_sym, b_sym, W_ne, W_es, W_ea2, b_ea2,
                                         res_n, res_e, node_out, edge_out);
}

// Round 5
// 578.245 us; speedup vs baseline: 1.9671x; 1.1293x over previous
//
#include <hip/hip_runtime.h>

#define DEVINL __device__ __forceinline__

// ---- problem constants (f32 problem) -----------------------------------
#define NLOC 1024
#define NNEI 64
#define NDIM 128
#define EDIM 64
#define ADIM 64
#define ASEL 20

// ---- static device workspace -------------------------------------------
enum : size_t {
  WS_NSELF = 0,                        // [1024,128] silu(node@W_self+b)
  WS_NW0   = WS_NSELF + 1024*128,      // [1024,128] node@W0 + b_ne
  WS_NV0   = WS_NW0   + 1024*128,      // [1024,64]  node@V0 + b_es
  WS_NA1   = WS_NV0   + 1024*64,       // [1024,64]  node@A1 + b_ea1
  WS_NB1   = WS_NA1   + 1024*64,       // [1024,64]  node@B1 + b_as
  WS_PA2   = WS_NB1   + 1024*64,       // [1024,20,64] e_ang @ A2
  WS_PA3   = WS_PA2   + 1024*ASEL*64,  // [1024,20,64] e_ang @ A3
  WS_PB2   = WS_PA3   + 1024*ASEL*64,  // [1024,20,64] e_ang @ B2
  WS_PB3   = WS_PB2   + 1024*ASEL*64,  // [1024,20,64] e_ang @ B3
  WS_NSYM  = WS_PB3   + 1024*ASEL*64,  // [1024,128] silu(cat@W_sym+b)
  WS_MSG   = WS_NSYM  + 1024*128,      // [1024,21,64] e_angle_msg (row20=bias)
  WS_F32_END = WS_MSG + 1024*21*64
};
__device__ float g_ws[WS_F32_END];
__device__ float g_red[1024*ASEL*64];   // reduced (K2 -> KN)

DEVINL float siluf(float x) {
  return x * __builtin_amdgcn_rcpf(1.0f + __expf(-x));
}

// =========================================================================
// K01: per-node projections + e_ang projections (merged k0+kp).
//   grid=1024 x 256. Waves 0-1 do node part + eang part; waves 2-3 eang only.
// =========================================================================
__global__ __launch_bounds__(256) void k01_pre(
    const float* __restrict__ node,
    const float* __restrict__ edge,
    const float* __restrict__ W_self, const float* __restrict__ b_self,
    const float* __restrict__ W_ne,   const float* __restrict__ b_ne,
    const float* __restrict__ W_es,   const float* __restrict__ b_es,
    const float* __restrict__ W_ea1,  const float* __restrict__ b_ea1,
    const float* __restrict__ W_as,   const float* __restrict__ b_as)
{
  const int l = blockIdx.x, t = threadIdx.x;
  __shared__ float nl[128];
  __shared__ float eang[ASEL*65];
  if (t < 128) nl[t] = node[l*128 + t];
  for (int e = t; e < ASEL*64; e += 256)
    eang[(e >> 6)*65 + (e & 63)] = edge[(size_t)l*4096 + e];
  __syncthreads();

  // ---- node projections (threads 0-127) --------------------------------
  if (t < 128) {
    float aS = b_self[t];
    float aW = b_ne[t];
    #pragma unroll 8
    for (int k = 0; k < 128; ++k) {
      float nv = nl[k];
      aS = fmaf(nv, W_self[k*128 + t], aS);
      aW = fmaf(nv, W_ne[k*128 + t], aW);
    }
    g_ws[WS_NSELF + l*128 + t] = siluf(aS);
    g_ws[WS_NW0   + l*128 + t] = aW;
    if (t < 64) {
      float aV = b_es[t], aA = b_ea1[t], aB = b_as[t];
      #pragma unroll 8
      for (int k = 0; k < 128; ++k) {
        float nv = nl[k];
        aV = fmaf(nv, W_es[k*64 + t], aV);
        aA = fmaf(nv, W_ea1[(64 + k)*64 + t], aA);
        aB = fmaf(nv, W_as[(64 + k)*64 + t], aB);
      }
      g_ws[WS_NV0 + l*64 + t] = aV;
      g_ws[WS_NA1 + l*64 + t] = aA;
      g_ws[WS_NB1 + l*64 + t] = aB;
    }
  }

  // ---- e_ang projections (all 256 threads) -----------------------------
  const int o = t & 63, wv = t >> 6;
  #pragma unroll 1
  for (int m = 0; m < 4; ++m) {
    const float* __restrict__ Wp =
          (m == 0) ? (W_ea1 + 192*64)
        : (m == 1) ? (W_ea1 + 256*64)
        : (m == 2) ? (W_as  + 192*64)
        :            (W_as  + 256*64);
    float* __restrict__ outp = g_ws +
          ((m == 0) ? WS_PA2 : (m == 1) ? WS_PA3 : (m == 2) ? WS_PB2 : WS_PB3)
        + (size_t)l*ASEL*64;
    float a0 = 0.f, a1 = 0.f, a2 = 0.f, a3 = 0.f, a4 = 0.f;
    #pragma unroll 4
    for (int k = 0; k < 64; ++k) {
      float w = Wp[k*64 + o];
      a0 = fmaf(eang[(wv     )*65 + k], w, a0);
      a1 = fmaf(eang[(wv +  4)*65 + k], w, a1);
      a2 = fmaf(eang[(wv +  8)*65 + k], w, a2);
      a3 = fmaf(eang[(wv + 12)*65 + k], w, a3);
      a4 = fmaf(eang[(wv + 16)*65 + k], w, a4);
    }
    outp[(wv     )*64 + o] = a0;
    outp[(wv +  4)*64 + o] = a1;
    outp[(wv +  8)*64 + o] = a2;
    outp[(wv + 12)*64 + o] = a3;
    outp[(wv + 16)*64 + o] = a4;
  }
}

// =========================================================================
// K2: angle kernel. grid = 1024*5, block 256, 4 blocks/CU.  (unchanged)
// =========================================================================
__global__ __launch_bounds__(256, 4) void k2_angle(
    const float* __restrict__ ang,
    const float* __restrict__ a_sw,
    const float* __restrict__ res_a,
    const float* __restrict__ W_ea1, const float* __restrict__ W_as,
    float* __restrict__ angle_out)
{
  const int bid = blockIdx.x;
  const int l = bid / 5, b = bid % 5;
  const int t = threadIdx.x;

  __shared__ __align__(16) float angl[80*68];               // 21.8 KB
  __shared__ __align__(16) float eA2l[ASEL*68], eB2l[ASEL*68]; // 10.9 KB
  __shared__ float aswl[ASEL];

  const float* __restrict__ angbase = ang + ((size_t)l*400 + b*80)*64;
  #pragma unroll
  for (int q = 0; q < 5; ++q) {
    int g = t + q*256;                 // float4 index 0..1279
    int lr = g >> 4, c4 = g & 15;
    float4 v = reinterpret_cast<const float4*>(angbase)[g];
    *reinterpret_cast<float4*>(&angl[lr*68 + c4*4]) = v;
  }
  {
    const float* __restrict__ pa2 = g_ws + WS_PA2 + (size_t)l*ASEL*64;
    const float* __restrict__ pb2 = g_ws + WS_PB2 + (size_t)l*ASEL*64;
    for (int g = t; g < ASEL*16; g += 256) {   // 320 float4 per mat
      int j = g >> 4, c4 = g & 15;
      *reinterpret_cast<float4*>(&eA2l[j*68 + c4*4]) =
          reinterpret_cast<const float4*>(pa2)[g];
      *reinterpret_cast<float4*>(&eB2l[j*68 + c4*4]) =
          reinterpret_cast<const float4*>(pb2)[g];
    }
  }
  if (t < ASEL) aswl[t] = a_sw[l*ASEL + t];

  const int cg = t & 15, rg = t >> 4;
  const int c0 = cg*4;
  const int i_loc = rg >> 2;           // 0..3 == wave index
  const int i = b*4 + i_loc;           // global i 0..19
  const int lr0 = rg*5;                // local row base

  float4 nA1v = *reinterpret_cast<const float4*>(g_ws + WS_NA1 + l*64 + c0);
  float4 nB1v = *reinterpret_cast<const float4*>(g_ws + WS_NB1 + l*64 + c0);
  float4 eA3v = *reinterpret_cast<const float4*>(g_ws + WS_PA3 + ((size_t)l*ASEL + i)*64 + c0);
  float4 eB3v = *reinterpret_cast<const float4*>(g_ws + WS_PB3 + ((size_t)l*ASEL + i)*64 + c0);
  float4 resav = *reinterpret_cast<const float4*>(res_a + c0);

  __syncthreads();                     // the only barrier

  const float* __restrict__ A0g = W_ea1;   // rows 0..63 = A0, [k][c]
  const float* __restrict__ B0g = W_as;    // rows 0..63 = B0

  float accA[20], accB[20];
  #pragma unroll
  for (int q = 0; q < 20; ++q) { accA[q] = 0.f; accB[q] = 0.f; }

  #pragma unroll 2
  for (int k = 0; k < 64; k += 4) {
    float vr[5][4];
    #pragma unroll
    for (int q = 0; q < 5; ++q)
      *reinterpret_cast<float4*>(vr[q]) =
          *reinterpret_cast<const float4*>(&angl[(lr0 + q)*68 + k]);
    #pragma unroll
    for (int kk = 0; kk < 4; ++kk) {
      float4 wA = *reinterpret_cast<const float4*>(A0g + (size_t)(k + kk)*64 + c0);
      float4 wB = *reinterpret_cast<const float4*>(B0g + (size_t)(k + kk)*64 + c0);
      #pragma unroll
      for (int q = 0; q < 5; ++q) {
        float av = vr[q][kk];
        accA[q*4+0] = fmaf(av, wA.x, accA[q*4+0]);
        accA[q*4+1] = fmaf(av, wA.y, accA[q*4+1]);
        accA[q*4+2] = fmaf(av, wA.z, accA[q*4+2]);
        accA[q*4+3] = fmaf(av, wA.w, accA[q*4+3]);
        accB[q*4+0] = fmaf(av, wB.x, accB[q*4+0]);
        accB[q*4+1] = fmaf(av, wB.y, accB[q*4+1]);
        accB[q*4+2] = fmaf(av, wB.z, accB[q*4+2]);
        accB[q*4+3] = fmaf(av, wB.w, accB[q*4+3]);
      }
    }
  }

  float red0 = 0.f, red1 = 0.f, red2 = 0.f, red3 = 0.f;
  #pragma unroll
  for (int q = 0; q < 5; ++q) {
    int lr = lr0 + q;
    int j = lr - i_loc*20;             // 0..19
    float aswj = aswl[j];
    float4 e2A = *reinterpret_cast<const float4*>(&eA2l[j*68 + c0]);
    float4 e2B = *reinterpret_cast<const float4*>(&eB2l[j*68 + c0]);
    float4 orig = *reinterpret_cast<const float4*>(&angl[lr*68 + c0]);

    float pA0 = accA[q*4+0] + nA1v.x + e2A.x + eA3v.x;
    float pA1 = accA[q*4+1] + nA1v.y + e2A.y + eA3v.y;
    float pA2 = accA[q*4+2] + nA1v.z + e2A.z + eA3v.z;
    float pA3 = accA[q*4+3] + nA1v.w + e2A.w + eA3v.w;
    red0 = fmaf(aswj, siluf(pA0), red0);
    red1 = fmaf(aswj, siluf(pA1), red1);
    red2 = fmaf(aswj, siluf(pA2), red2);
    red3 = fmaf(aswj, siluf(pA3), red3);

    float pB0 = accB[q*4+0] + nB1v.x + e2B.x + eB3v.x;
    float pB1 = accB[q*4+1] + nB1v.y + e2B.y + eB3v.y;
    float pB2 = accB[q*4+2] + nB1v.z + e2B.z + eB3v.z;
    float pB3 = accB[q*4+3] + nB1v.w + e2B.w + eB3v.w;
    float4 outv;
    outv.x = orig.x + resav.x * siluf(pB0);
    outv.y = orig.y + resav.y * siluf(pB1);
    outv.z = orig.z + resav.z * siluf(pB2);
    outv.w = orig.w + resav.w * siluf(pB3);
    *reinterpret_cast<float4*>(angle_out + ((size_t)l*400 + b*80 + lr)*64 + c0) = outv;
  }

  red0 += __shfl_xor(red0, 16); red0 += __shfl_xor(red0, 32);
  red1 += __shfl_xor(red1, 16); red1 += __shfl_xor(red1, 32);
  red2 += __shfl_xor(red2, 16); red2 += __shfl_xor(red2, 32);
  red3 += __shfl_xor(red3, 16); red3 += __shfl_xor(red3, 32);
  if ((t & 0x30) == 0) {
    float sc = aswl[i] * 0.22360679775f;   // asw[i] / sqrt(20)
    float4 o4 = make_float4(red0*sc, red1*sc, red2*sc, red3*sc);
    *reinterpret_cast<float4*>(g_red + ((size_t)l*ASEL + i)*64 + c0) = o4;
  }
}

// =========================================================================
// KN: hg / cat / nsym / e_angle_msg.  grid=1024 x 256, ~12 KB LDS ->
//   8 blocks/CU (32 waves) -> latency hidden by TLP instead of sitting on
//   k3's 2-block critical path.
// =========================================================================
__global__ __launch_bounds__(256) void kn_sym(
    const float* __restrict__ node_ext,
    const float* __restrict__ edge,
    const float* __restrict__ h2,
    const float* __restrict__ sw,
    const int* __restrict__ nlist,
    const float* __restrict__ W_sym, const float* __restrict__ b_sym,
    const float* __restrict__ W_ea2, const float* __restrict__ b_ea2)
{
  const int l = blockIdx.x, t = threadIdx.x;
  __shared__ float hwv[64*4];
  __shared__ int   idxl[64];
  __shared__ float gredl[ASEL*64];
  __shared__ float hgE[3*64], hgN[3*128];
  __shared__ float cat[768];
  __shared__ float nsymp[2][128];

  if (t < 64) {
    idxl[t] = nlist[l*64 + t];
    float s = sw[l*64 + t];
    hwv[t*4+0] = h2[(l*64 + t)*3 + 0] * s;
    hwv[t*4+1] = h2[(l*64 + t)*3 + 1] * s;
    hwv[t*4+2] = h2[(l*64 + t)*3 + 2] * s;
  }
  for (int e = t; e < ASEL*64; e += 256)
    gredl[e] = g_red[(size_t)l*ASEL*64 + e];
  __syncthreads();

  // ---- hg = (h2*sw)^T @ {Ef, Nf} / 64 (direct from global/L2) ----------
  for (int e = t; e < 576; e += 256) {
    if (e < 192) {
      int tt = e >> 6, d = e & 63;
      float acc = 0.f;
      #pragma unroll 4
      for (int n = 0; n < 64; ++n)
        acc = fmaf(hwv[n*4 + tt], edge[(size_t)l*4096 + n*64 + d], acc);
      hgE[tt*64 + d] = acc * (1.f/64.f);
    } else {
      int e2 = e - 192;
      int tt = e2 >> 7, k = e2 & 127;
      float acc = 0.f;
      #pragma unroll 4
      for (int n = 0; n < 64; ++n)
        acc = fmaf(hwv[n*4 + tt], node_ext[(size_t)idxl[n]*128 + k], acc);
      hgN[tt*128 + k] = acc * (1.f/64.f);
    }
  }
  __syncthreads();

  // ---- cat = [grrg(edge)(4x64), grrg(nei)(4x128)] ----------------------
  {
    int e = t;   // 256 items
    int a = e >> 6, d = e & 63;
    cat[e] = (hgE[a]*hgE[d] + hgE[64 + a]*hgE[64 + d] + hgE[128 + a]*hgE[128 + d]) * (1.f/3.f);
  }
  for (int e = t; e < 512; e += 256) {
    int a = e >> 7, k = e & 127;
    cat[256 + e] = (hgN[a]*hgN[k] + hgN[128 + a]*hgN[128 + k] + hgN[256 + a]*hgN[256 + k]) * (1.f/3.f);
  }
  __syncthreads();

  // ---- nsym: k-split over two thread halves ----------------------------
  {
    const int c = t & 127, half = t >> 7;
    const int k0 = half*384;
    float acc = half ? 0.f : b_sym[c];
    #pragma unroll 8
    for (int k = 0; k < 384; ++k)
      acc = fmaf(cat[k0 + k], W_sym[(size_t)(k0 + k)*128 + c], acc);
    nsymp[half][c] = acc;
  }
  __syncthreads();
  if (t < 128)
    g_ws[WS_NSYM + l*128 + t] = siluf(nsymp[0][t] + nsymp[1][t]);

  // ---- e_angle_msg: 21x64 table (row 20 = silu(bias) const row) --------
  for (int e = t; e < 21*64; e += 256) {
    int n = e >> 6, o = e & 63;
    float acc = b_ea2[o];
    if (n < ASEL) {
      #pragma unroll 4
      for (int k = 0; k < 64; ++k)
        acc = fmaf(gredl[n*64 + k], W_ea2[k*64 + o], acc);
    }
    g_ws[WS_MSG + (size_t)l*21*64 + e] = siluf(acc);
  }
}

// =========================================================================
// K3: node + edge GEMM only.  grid=1024 x 256, 2 blocks/CU.
//   C[64x192] = AL[64x192] @ W[192x192]; AL=[Nf|Ef] LDS stride 196;
//   W staged in 12 x 16-k chunks with register prefetch (T14).
//   Epilogue: es-cols -> edge_out (msg from g_ws); ne-cols -> shfl +
//   LDS-atomic n-reduction -> node_out (nsym from g_ws).
// =========================================================================
__global__ __launch_bounds__(256, 2) void k3_node_edge(
    const float* __restrict__ node_ext,
    const float* __restrict__ edge,
    const float* __restrict__ sw,
    const int* __restrict__ nlist,
    const float* __restrict__ W_ne,  const float* __restrict__ W_es,
    const float* __restrict__ res_n, const float* __restrict__ res_e,
    float* __restrict__ node_out,
    float* __restrict__ edge_out)
{
  const int l = blockIdx.x, t = threadIdx.x;
  __shared__ __align__(16) float AL[64*196];   // 50.2 KB
  __shared__ __align__(16) float WL[16*192];   // 12 KB
  __shared__ float swl[64];
  __shared__ float redn[128];
  __shared__ int   idxl[64];

  if (t < 64) { idxl[t] = nlist[l*64 + t]; swl[t] = sw[l*64 + t]; }
  if (t >= 128) redn[t - 128] = 0.f;
  __syncthreads();   // idxl ready

  // prefetch W chunk 0 into registers (3 float4 per thread)
  float4 wreg[3];
  #pragma unroll
  for (int q = 0; q < 3; ++q) {
    int g = q*256 + t;                 // 0..767
    int kk = g / 48, c4 = g % 48;
    int c = c4*4, krow = 128 + kk;
    wreg[q] = (c < 128)
        ? *reinterpret_cast<const float4*>(W_ne + (size_t)krow*128 + c)
        : *reinterpret_cast<const float4*>(W_es + (size_t)krow*64 + (c - 128));
  }

  // ---- stage AL: Nf gather (2048 float4) + Ef (1024 float4) ------------
  for (int g = t; g < 2048; g += 256) {
    int n = g >> 5, q = g & 31;
    float4 v = *reinterpret_cast<const float4*>(node_ext + (size_t)idxl[n]*128 + q*4);
    *reinterpret_cast<float4*>(&AL[n*196 + q*4]) = v;
  }
  for (int g = t; g < 1024; g += 256) {
    int n = g >> 4, q = g & 15;
    float4 v = *reinterpret_cast<const float4*>(edge + (size_t)l*4096 + n*64 + q*4);
    *reinterpret_cast<float4*>(&AL[n*196 + 128 + q*4]) = v;
  }

  // ---- main GEMM: C[64x192] = AL @ W, K-chunks of 16 -------------------
  const int tx = t & 15, ty = t >> 4;
  const int n0 = ty*4, c0 = tx*12;

  float acc[4][12];
  #pragma unroll
  for (int r = 0; r < 4; ++r)
    #pragma unroll
    for (int cc = 0; cc < 12; ++cc) acc[r][cc] = 0.f;

  #pragma unroll 1
  for (int kb = 0; kb < 12; ++kb) {
    __syncthreads();                   // kb=0: AL staged; else: WL free
    #pragma unroll
    for (int q = 0; q < 3; ++q) {
      int g = q*256 + t;
      int kk = g / 48, c4 = g % 48;
      *reinterpret_cast<float4*>(&WL[kk*192 + c4*4]) = wreg[q];
    }
    if (kb < 11) {                     // issue next-chunk loads early (T14)
      #pragma unroll
      for (int q = 0; q < 3; ++q) {
        int g = q*256 + t;
        int kk = g / 48, c4 = g % 48;
        int c = c4*4, krow = 128 + (kb + 1)*16 + kk;
        wreg[q] = (c < 128)
            ? *reinterpret_cast<const float4*>(W_ne + (size_t)krow*128 + c)
            : *reinterpret_cast<const float4*>(W_es + (size_t)krow*64 + (c - 128));
      }
    }
    __syncthreads();                   // WL ready

    const int kbase = kb*16;
    #pragma unroll
    for (int kk = 0; kk < 16; kk += 4) {
      float ar[4][4];
      #pragma unroll
      for (int r = 0; r < 4; ++r)
        *reinterpret_cast<float4*>(ar[r]) =
            *reinterpret_cast<const float4*>(&AL[(n0 + r)*196 + kbase + kk]);
      #pragma unroll
      for (int j = 0; j < 4; ++j) {
        float4 w0 = *reinterpret_cast<const float4*>(&WL[(kk + j)*192 + c0]);
        float4 w1 = *reinterpret_cast<const float4*>(&WL[(kk + j)*192 + c0 + 4]);
        float4 w2 = *reinterpret_cast<const float4*>(&WL[(kk + j)*192 + c0 + 8]);
        #pragma unroll
        for (int r = 0; r < 4; ++r) {
          float av = ar[r][j];
          acc[r][0]  = fmaf(av, w0.x, acc[r][0]);
          acc[r][1]  = fmaf(av, w0.y, acc[r][1]);
          acc[r][2]  = fmaf(av, w0.z, acc[r][2]);
          acc[r][3]  = fmaf(av, w0.w, acc[r][3]);
          acc[r][4]  = fmaf(av, w1.x, acc[r][4]);
          acc[r][5]  = fmaf(av, w1.y, acc[r][5]);
          acc[r][6]  = fmaf(av, w1.z, acc[r][6]);
          acc[r][7]  = fmaf(av, w1.w, acc[r][7]);
          acc[r][8]  = fmaf(av, w2.x, acc[r][8]);
          acc[r][9]  = fmaf(av, w2.y, acc[r][9]);
          acc[r][10] = fmaf(av, w2.z, acc[r][10]);
          acc[r][11] = fmaf(av, w2.w, acc[r][11]);
        }
      }
    }
  }

  // ---- epilogue --------------------------------------------------------
  float colb[12];
  #pragma unroll
  for (int cc = 0; cc < 12; ++cc) {
    int c = c0 + cc;
    colb[cc] = (c < 128) ? g_ws[WS_NW0 + l*128 + c]
                         : g_ws[WS_NV0 + l*64 + (c - 128)];
  }
  const float* __restrict__ msgb = g_ws + WS_MSG + (size_t)l*21*64;
  float np[12];
  #pragma unroll
  for (int cc = 0; cc < 12; ++cc) np[cc] = 0.f;

  #pragma unroll
  for (int r = 0; r < 4; ++r) {
    int n = n0 + r;
    float sn = swl[n];
    #pragma unroll
    for (int cc = 0; cc < 12; ++cc) {
      int c = c0 + cc;
      float s = siluf(acc[r][cc] + colb[cc]);
      if (c < 128) {
        np[cc] = fmaf(s, sn, np[cc]);
      } else {
        int o = c - 128;
        float msgv = msgb[((n < ASEL) ? n : ASEL)*64 + o];
        float ef = AL[n*196 + 128 + o];
        edge_out[(size_t)l*4096 + n*64 + o] =
            ef + res_e[o]*s + res_e[64 + o]*msgv;
      }
    }
  }

  #pragma unroll
  for (int cc = 0; cc < 12; ++cc) {
    np[cc] += __shfl_xor(np[cc], 16);
    np[cc] += __shfl_xor(np[cc], 32);
  }
  if ((ty & 3) == 0) {                 // one lane per (wave, col)
    #pragma unroll
    for (int cc = 0; cc < 12; ++cc) {
      int c = c0 + cc;
      if (c < 128) atomicAdd(&redn[c], np[cc]);
    }
  }
  __syncthreads();

  if (t < 128) {
    const int c = t;
    float nedge = redn[c] * (1.f/64.f);
    float nodev = node_ext[l*128 + c];
    node_out[l*128 + c] = nodev + res_n[c]*g_ws[WS_NSELF + l*128 + c]
                        + res_n[128 + c]*g_ws[WS_NSYM + l*128 + c]
                        + res_n[256 + c]*nedge;
  }
}

// =========================================================================
extern "C" void kernel_launch(void* const* d_in, const int* in_sizes, int n_in,
                              void* d_out, int out_size, void* d_ws, size_t ws_size,
                              hipStream_t stream) {
  const float* node_ext = (const float*)d_in[0];
  const float* edge_ebd = (const float*)d_in[1];
  const float* h2       = (const float*)d_in[2];
  const float* angle    = (const float*)d_in[3];
  const float* sw       = (const float*)d_in[4];
  const float* a_sw     = (const float*)d_in[5];
  const float* W_self   = (const float*)d_in[6];
  const float* b_self   = (const float*)d_in[7];
  const float* W_sym    = (const float*)d_in[8];
  const float* b_sym    = (const float*)d_in[9];
  const float* W_ne     = (const float*)d_in[10];
  const float* b_ne     = (const float*)d_in[11];
  const float* W_es     = (const float*)d_in[12];
  const float* b_es     = (const float*)d_in[13];
  const float* W_ea1    = (const float*)d_in[14];
  const float* b_ea1    = (const float*)d_in[15];
  const float* W_ea2    = (const float*)d_in[16];
  const float* b_ea2    = (const float*)d_in[17];
  const float* W_as     = (const float*)d_in[18];
  const float* b_as     = (const float*)d_in[19];
  const float* res_n    = (const float*)d_in[20];
  const float* res_e    = (const float*)d_in[21];
  const float* res_a    = (const float*)d_in[22];
  const int*   nlist    = (const int*)d_in[23];

  float* out = (float*)d_out;
  float* node_out  = out;
  float* edge_out  = out + 1024*128;
  float* angle_out = out + 1024*128 + (size_t)1024*64*64;

  k01_pre<<<1024, 256, 0, stream>>>(node_ext, edge_ebd, W_self, b_self,
                                    W_ne, b_ne, W_es, b_es, W_ea1, b_ea1,
                                    W_as, b_as);
  k2_angle<<<1024*5, 256, 0, stream>>>(angle, a_sw, res_a,
                                       W_ea1, W_as, angle_out);
  kn_sym<<<1024, 256, 0, stream>>>(node_ext, edge_ebd, h2, sw, nlist,
                                   W_sym, b_sym, W_ea2, b_ea2);
  k3_node_edge<<<1024, 256, 0, stream>>>(node_ext, edge_ebd, sw, nlist,
                                         W_ne, W_es, res_n, res_e,
                                         node_out, edge_out);
}